// Round 3
// baseline (124.201 us; speedup 1.0000x reference)
//
#include <hip/hip_runtime.h>

// (B,P,D,H,DB) = (2048,128,64,8,10)
// Fully fused, algebraically factored:
//   dots[p,h] = 0.125*(dot0[h] + sum_e b[p,e]*Wqkb[e,h])
//   softmax over h; A[h]=sum_p attn, S[e,h]=sum_p attn*b[p,e]
//   vals[h,d] = A[h]*(xv+biases) + sum_e S[e,h]*W_kvb[e,512+h*64+d]
//   out = vals @ W_f + b_f
// 512 blocks x 256 thr (4 rows/block, 2 blocks/CU — grid-capped occupancy,
// so the design goal is a short per-block critical path + wave drift).
#define NDB 10

__global__ __launch_bounds__(256) void fused_attn(
    const float* __restrict__ x, const float* __restrict__ bmat,
    const float* __restrict__ W_kvx, const float* __restrict__ b_kvx,
    const float* __restrict__ W_kvb, const float* __restrict__ b_kvb,
    const float* __restrict__ W_q, const float* __restrict__ b_q,
    const float* __restrict__ W_f, const float* __restrict__ b_f,
    float* __restrict__ out)
{
    __shared__ float x_t[4][64];          //  1 KB   [r][k]
    __shared__ float bb_s[4][1280];       // 20 KB   written AFTER phase B
    __shared__ float xp_s[4][1024];       // 16 KB
    __shared__ float q_s[4][512];         //  8 KB
    __shared__ float dot0_s[4][8];
    __shared__ float Wqkb_s[4][NDB][8];
    __shared__ float A_s[4][8];
    __shared__ float S_s[4][NDB][8];
    __shared__ float vals_s[4][512];      //  8 KB   [r][f]
    __shared__ float pout[4][4][64];      //  4 KB   [fs][r][j]
    // total ~61 KB (<64 KB static limit), 2 blocks/CU

    const int t = threadIdx.x;
    const int b0 = blockIdx.x * 4;
    const int lane = t & 63;
    const int w = t >> 6;                 // wave id == row id for C/C2/vals

    // ---- Phase A: x load (waited), bb loads issued & HELD IN REGS thru B ----
    float xval = x[b0 * 64 + t];                       // issued first
    float4 bbreg[5];
    const float4* bsrc = (const float4*)(bmat + (size_t)b0 * 1280);
    #pragma unroll
    for (int it = 0; it < 5; ++it) bbreg[it] = bsrc[t + 256 * it];
    x_t[t >> 6][t & 63] = xval;                        // waits only x (vmcnt(5))
    __syncthreads();                                   // barrier 1

    // ---- Phase B: proj GEMM. cols {c*256+t}: 4 kv cols + 2 q cols, 4 rows ----
    float accKV[4][4] = {};
    float accQ[4][2] = {};
    {
        const float* pkv = W_kvx + t;
        const float* pq  = W_q + t;
        #pragma unroll 4
        for (int k0 = 0; k0 < 64; k0 += 4) {
            float4 xr[4];
            #pragma unroll
            for (int r = 0; r < 4; ++r) xr[r] = *(const float4*)&x_t[r][k0]; // broadcast b128
            #pragma unroll
            for (int kk = 0; kk < 4; ++kk) {
                const int k = k0 + kk;
                float wk0 = pkv[k * 1024];
                float wk1 = pkv[k * 1024 + 256];
                float wk2 = pkv[k * 1024 + 512];
                float wk3 = pkv[k * 1024 + 768];
                float wq0 = pq[k * 512];
                float wq1 = pq[k * 512 + 256];
                #pragma unroll
                for (int r = 0; r < 4; ++r) {
                    float xv = ((const float*)&xr[r])[kk];
                    accKV[r][0] = fmaf(xv, wk0, accKV[r][0]);
                    accKV[r][1] = fmaf(xv, wk1, accKV[r][1]);
                    accKV[r][2] = fmaf(xv, wk2, accKV[r][2]);
                    accKV[r][3] = fmaf(xv, wk3, accKV[r][3]);
                    accQ[r][0]  = fmaf(xv, wq0, accQ[r][0]);
                    accQ[r][1]  = fmaf(xv, wq1, accQ[r][1]);
                }
            }
        }
    }
    // biases folded; write xp/q; dump bb regs into LDS (HBM latency now hidden)
    {
        #pragma unroll
        for (int c = 0; c < 4; ++c) {
            int f = c * 256 + t;
            float bias = b_kvx[f] + b_kvb[f];
            #pragma unroll
            for (int r = 0; r < 4; ++r) xp_s[r][f] = accKV[r][c] + bias;
        }
        #pragma unroll
        for (int c = 0; c < 2; ++c) {
            int fq = c * 256 + t;
            float bias = b_q[fq];
            #pragma unroll
            for (int r = 0; r < 4; ++r) q_s[r][fq] = accQ[r][c] + bias;
        }
        float4* bbdst = (float4*)bb_s;
        #pragma unroll
        for (int it = 0; it < 5; ++it) bbdst[t + 256 * it] = bbreg[it];
    }
    __syncthreads();                                   // barrier 2

    // ======= per-wave region: wave w owns row r=w; NO barriers needed =======
    const int r = w;

    // ---- Phase C: dot0[h], Wqkb[e][h] via 8-lane-group dots ----
    {
        int h = lane >> 3, i8 = lane & 7;
        float s = 0.f;
        #pragma unroll
        for (int j = 0; j < 8; ++j) {
            int d = h * 64 + i8 + j * 8;
            s = fmaf(xp_s[r][d], q_s[r][d], s);
        }
        s += __shfl_xor(s, 1); s += __shfl_xor(s, 2); s += __shfl_xor(s, 4);
        if (i8 == 0) dot0_s[r][h] = s;
    }
    {
        int g = lane >> 3, l = lane & 7;
        #pragma unroll
        for (int e = 0; e < NDB; ++e) {
            float s = 0.f;
            #pragma unroll
            for (int m = 0; m < 8; ++m) {
                int d = g * 64 + l + m * 8;
                s = fmaf(W_kvb[e * 1024 + d], q_s[r][d], s);
            }
            s += __shfl_xor(s, 1); s += __shfl_xor(s, 2); s += __shfl_xor(s, 4);
            if (l == 0) Wqkb_s[r][e][g] = s;
        }
    }

    // ---- Phase C2: dots + softmax(h) + A/S accumulation (in-wave) ----
    {
        int h = lane & 7, pg = lane >> 3;
        float aA = 0.f, aS[NDB];
        #pragma unroll
        for (int e = 0; e < NDB; ++e) aS[e] = 0.f;
        #pragma unroll 4
        for (int it = 0; it < 16; ++it) {
            int p = pg + 8 * it;
            float bbv[NDB];
            #pragma unroll
            for (int e = 0; e < NDB; ++e) bbv[e] = bb_s[r][p * NDB + e];
            float dot = dot0_s[r][h];
            #pragma unroll
            for (int e = 0; e < NDB; ++e) dot = fmaf(bbv[e], Wqkb_s[r][e][h], dot);
            dot *= 0.125f;
            float m = dot;
            m = fmaxf(m, __shfl_xor(m, 1));
            m = fmaxf(m, __shfl_xor(m, 2));
            m = fmaxf(m, __shfl_xor(m, 4));
            float ex = __expf(dot - m);
            float sum = ex;
            sum += __shfl_xor(sum, 1); sum += __shfl_xor(sum, 2); sum += __shfl_xor(sum, 4);
            float at = ex * __builtin_amdgcn_rcpf(sum);
            aA += at;
            #pragma unroll
            for (int e = 0; e < NDB; ++e) aS[e] = fmaf(at, bbv[e], aS[e]);
        }
        aA += __shfl_xor(aA, 8); aA += __shfl_xor(aA, 16); aA += __shfl_xor(aA, 32);
        #pragma unroll
        for (int e = 0; e < NDB; ++e) {
            aS[e] += __shfl_xor(aS[e], 8);
            aS[e] += __shfl_xor(aS[e], 16);
            aS[e] += __shfl_xor(aS[e], 32);
        }
        if (pg == 0) {
            A_s[r][h] = aA;
            #pragma unroll
            for (int e = 0; e < NDB; ++e) S_s[r][e][h] = aS[e];
        }
    }

    // ---- vals (same wave): vals_s[r][f], conflict-free writes ----
    #pragma unroll
    for (int i = 0; i < 8; ++i) {
        int f = lane + 64 * i;             // h = i
        float v = A_s[r][i] * xp_s[r][512 + f];
        #pragma unroll
        for (int e = 0; e < NDB; ++e)
            v = fmaf(S_s[r][e][i], W_kvb[e * 1024 + 512 + f], v);
        vals_s[r][f] = v;
    }
    __syncthreads();                                   // barrier 3 (cross-wave D)

    // ---- Phase D: out = vals @ W_f + b_f ; f-slice fs per wave ----
    {
        const int j = t & 63, fs = t >> 6;
        float acc[4] = {};
        #pragma unroll 4
        for (int f0 = fs * 128; f0 < fs * 128 + 128; f0 += 4) {
            float w0 = W_f[(f0 + 0) * 64 + j];
            float w1 = W_f[(f0 + 1) * 64 + j];
            float w2 = W_f[(f0 + 2) * 64 + j];
            float w3 = W_f[(f0 + 3) * 64 + j];
            #pragma unroll
            for (int rr = 0; rr < 4; ++rr) {
                float4 v = *(const float4*)&vals_s[rr][f0];  // lane-uniform broadcast
                acc[rr] = fmaf(v.x, w0, acc[rr]);
                acc[rr] = fmaf(v.y, w1, acc[rr]);
                acc[rr] = fmaf(v.z, w2, acc[rr]);
                acc[rr] = fmaf(v.w, w3, acc[rr]);
            }
        }
        #pragma unroll
        for (int rr = 0; rr < 4; ++rr) pout[fs][rr][j] = acc[rr];
    }
    __syncthreads();                                   // barrier 4
    {
        const int rr = t >> 6, j = t & 63;
        float o = b_f[j];
        #pragma unroll
        for (int fs = 0; fs < 4; ++fs) o += pout[fs][rr][j];
        out[(size_t)(b0 + rr) * 64 + j] = o;
    }
}

extern "C" void kernel_launch(void* const* d_in, const int* in_sizes, int n_in,
                              void* d_out, int out_size, void* d_ws, size_t ws_size,
                              hipStream_t stream)
{
    const float* x     = (const float*)d_in[0];
    const float* bmat  = (const float*)d_in[1];
    const float* W_kvx = (const float*)d_in[2];
    const float* b_kvx = (const float*)d_in[3];
    const float* W_kvb = (const float*)d_in[4];
    const float* b_kvb = (const float*)d_in[5];
    const float* W_q   = (const float*)d_in[6];
    const float* b_q   = (const float*)d_in[7];
    const float* W_f   = (const float*)d_in[8];
    const float* b_f   = (const float*)d_in[9];
    float* out = (float*)d_out;

    fused_attn<<<512, 256, 0, stream>>>(x, bmat, W_kvx, b_kvx, W_kvb, b_kvb,
                                        W_q, b_q, W_f, b_f, out);
}